// Round 7
// baseline (429.595 us; speedup 1.0000x reference)
//
#include <hip/hip_runtime.h>

// LocalAffinity: out[k,t,z,y,x] = x[k,z,y,x] - x[k,clamp(z+di*d),clamp(y+dj*d),clamp(x+dk*d)]
// 26 taps (raster (i,j,k) minus center) at d=1 then d=2. B=1,K=2,D=64,H=128,W=128.
// R7: persistent blocks + register double-buffered pipeline.
// All prior variants: each wave writes 4-52KB then dies -> per-wave vmcnt(0)
// end-drain + launch/ramp overhead at 4KB granularity caps writes at ~3 TB/s
// (fill waves loop over MBs with no waits -> 6.3 TB/s). Fix: 2048 blocks x 13
// chunks each; prefetch chunk i+1's loads BEFORE chunk i's stores so the
// counted vmcnt wait for loads never forces store retirement.

constexpr int Dz   = 64;
constexpr int Hy   = 128;
constexpr int Wx   = 128;
constexpr int HW   = Hy * Wx;        // 16384
constexpr int DHW  = Dz * HW;        // 1048576
constexpr int TAPS = 52;
constexpr int NBLK  = 2048;
constexpr int NITER = 13;            // 2048*13 = 26624 = 2*52*64*4 chunks

typedef float floatx4   __attribute__((ext_vector_type(4)));
typedef float floatx4_u __attribute__((ext_vector_type(4), aligned(4)));

__device__ __forceinline__ int iclamp(int v, int lo, int hi) {
    return v < lo ? lo : (v > hi ? hi : v);
}

// Issue the 8 loads for one 16KB chunk (raw; edge-lane repair happens at store).
__device__ __forceinline__ void load_chunk(const float* __restrict__ in,
                                           int chunk, int tid,
                                           floatx4* cc, floatx4* ss) {
    const int q   = chunk & 3;
    const int z   = (chunk >> 2) & 63;
    const int b3  = chunk >> 8;          // 0..103 = k*52 + t
    const int t   = b3 % TAPS;
    const int k   = b3 / TAPS;
    const int d   = (t < 26) ? 1 : 2;
    const int t26 = (t < 26) ? t : t - 26;
    const int ras = (t26 < 13) ? t26 : t26 + 1;
    const int di  = ras / 9 - 1;
    const int dj  = (ras % 9) / 3 - 1;
    const int dk  = (ras % 3) - 1;
    const int dkd = dk * d;
    const int dy  = dj * d;
    const int zc  = iclamp(z + di * d, 0, Dz - 1);

    const float* ctr = in + k * DHW + z  * HW;
    const float* src = in + k * DHW + zc * HW;
    const int x0 = (tid & 31) << 2;
    const int yb = (q << 5) | (tid >> 5);

    #pragma unroll
    for (int p = 0; p < 4; ++p) {
        const int y = yb + (p << 3);
        cc[p] = *(const floatx4*)(ctr + y * Wx + x0);
        const int yc = iclamp(y + dy, 0, Hy - 1);
        const float* row = src + yc * Wx;
        if (dkd == 0) {
            ss[p] = *(const floatx4*)(row + x0);
        } else {
            const int xsa = iclamp(x0 + dkd, 0, Wx - 4);  // start clamped in-row
            ss[p] = *(const floatx4_u*)(row + xsa);
        }
    }
}

// Repair edge lanes, subtract, store 16KB chunk (nontemporal).
__device__ __forceinline__ void store_chunk(float* __restrict__ out,
                                            int chunk, int tid,
                                            const floatx4* cc, const floatx4* ss) {
    const int q   = chunk & 3;
    const int z   = (chunk >> 2) & 63;
    const int b3  = chunk >> 8;
    const int t   = b3 % TAPS;
    const int k   = b3 / TAPS;
    const int d   = (t < 26) ? 1 : 2;
    const int t26 = (t < 26) ? t : t - 26;
    const int ras = (t26 < 13) ? t26 : t26 + 1;
    const int dk  = (ras % 3) - 1;
    const int dkd = dk * d;
    const int x4  = tid & 31;
    const int x0  = x4 << 2;
    const int yb  = (q << 5) | (tid >> 5);

    float* obase = out + (size_t)(k * TAPS + t) * (size_t)DHW + (size_t)z * HW;

    #pragma unroll
    for (int p = 0; p < 4; ++p) {
        const floatx4 v = ss[p];
        floatx4 sv = v;
        if (dkd < 0) {                  // block-uniform branch
            const bool e = (x4 == 0);   // per-lane predication (verified R2-R6)
            if (dkd == -1) {
                if (e) { sv.x = v.x; sv.y = v.x; sv.z = v.y; sv.w = v.z; }
            } else {                    // dkd == -2
                if (e) { sv.x = v.x; sv.y = v.x; sv.z = v.x; sv.w = v.y; }
            }
        } else if (dkd > 0) {
            const bool e = (x4 == 31);
            if (dkd == 1) {
                if (e) { sv.x = v.y; sv.y = v.z; sv.z = v.w; sv.w = v.w; }
            } else {                    // dkd == 2
                if (e) { sv.x = v.z; sv.y = v.w; sv.z = v.w; sv.w = v.w; }
            }
        }
        const floatx4 c = cc[p];
        floatx4 r;
        r.x = c.x - sv.x; r.y = c.y - sv.y;
        r.z = c.z - sv.z; r.w = c.w - sv.w;
        const int y = yb + (p << 3);
        __builtin_nontemporal_store(r, (floatx4*)(obase + y * Wx + x0));
    }
}

__global__ __launch_bounds__(256)
void LocalAffinity_kernel(const float* __restrict__ in, float* __restrict__ out) {
    const int bid = blockIdx.x;
    const int tid = threadIdx.x;

    // Register double-buffer; full unroll keeps all indices static (no scratch).
    floatx4 Ac[4], As[4], Bc[4], Bs[4];
    load_chunk(in, bid, tid, Ac, As);

    #pragma unroll
    for (int it = 0; it < NITER; ++it) {
        const int chunk = it * NBLK + bid;     // linear sliding output window
        if (it + 1 < NITER) {                  // prefetch next chunk FIRST:
            if (it & 1) load_chunk(in, chunk + NBLK, tid, Ac, As);
            else        load_chunk(in, chunk + NBLK, tid, Bc, Bs);
        }
        // stores issued AFTER the prefetch loads -> waiting for those loads
        // next iteration never forces these stores to retire (vmcnt in-order).
        if (it & 1) store_chunk(out, chunk, tid, Bc, Bs);
        else        store_chunk(out, chunk, tid, Ac, As);
    }
}

extern "C" void kernel_launch(void* const* d_in, const int* in_sizes, int n_in,
                              void* d_out, int out_size, void* d_ws, size_t ws_size,
                              hipStream_t stream) {
    const float* x = (const float*)d_in[0];
    float* out = (float*)d_out;
    LocalAffinity_kernel<<<NBLK, 256, 0, stream>>>(x, out);
}